// Round 15
// baseline (280.207 us; speedup 1.0000x reference)
//
#include <hip/hip_runtime.h>

// MetaPathGNN — only the edge2 (B->C) layer + output GEMM matter.
//
// R15: k_fused re-tiled: waves split COLUMNS (128r x 32c each), A chunks
// (128r x 32k bf16 hi+lo, 16KB) staged once per block via global_load_lds
// and shared by all 4 waves.  A is pre-split to bf16 hi/lo planes in global
// (gather writes aggh/aggl; prep splits xC->xch/xcl) so K2 A-frags are raw
// ds_read_b128 — zero cvt VALU, bank-balanced without swizzle.  B-plane L2
// traffic per block drops 640KB->256KB.  LN via cross-wave LDS partials;
// K3 per-32-row group from recycled LDS.  LDS 20KB, VGPR ~120.
//
// ws (ints): [cnt N | fillc N | offs N | part 128 | tot 4 | srcw 2E |
//             wlh/wll/wch/wcl 16384u16 | woh/wol 8192u16 | bc 128f |
//             aggh | aggl | xch | xcl (each N*128 u16)]

#define HD 128
#define OD 64
#define SCAN_E 1024

typedef unsigned short u16;
typedef short v8s __attribute__((ext_vector_type(8)));
typedef float v4f __attribute__((ext_vector_type(4)));

union Frag {
    unsigned int u[4];
    uint4 q;
    v8s v;
    u16 h[8];
};

__device__ __forceinline__ float softplus_f(float x) {
    return fmaxf(x, 0.0f) + log1pf(expf(-fabsf(x)));
}
__device__ __forceinline__ float sigmoid_f(float x) {
    return 1.0f / (1.0f + expf(-x));
}
// swizzled LDS offset within a [32][128] fp32 slab: 16B granule XOR row&7
__device__ __forceinline__ int swz(int r, int c) {
    int g = (c >> 2) ^ (r & 7);
    return r * 128 + g * 4 + (c & 3);
}

// async 16B global->LDS (lds dest wave-uniform; HW puts lane i at +i*16)
__device__ __forceinline__ void gload_lds16(const void* g, void* l) {
    __builtin_amdgcn_global_load_lds(
        (const __attribute__((address_space(1))) void*)g,
        (__attribute__((address_space(3))) void*)l, 16, 0, 0);
}

// split x into bf16 hi + bf16 lo (truncation split; residual ~2^-17 |x|)
__device__ __forceinline__ void split_store(float x, u16* ph, u16* pl) {
    unsigned int b = __float_as_uint(x);
    unsigned int h = b & 0xffff0000u;
    *ph = (u16)(h >> 16);
    float r = x - __uint_as_float(h);
    *pl = (u16)(__float_as_uint(r) >> 16);
}

// 8 floats -> ushort8 hi plane + ushort8 lo plane
__device__ __forceinline__ void split_pack8(const float* f, Frag* hi, Frag* lo) {
#pragma unroll
    for (int j = 0; j < 8; ++j) {
        unsigned int b = __float_as_uint(f[j]);
        unsigned int h = b & 0xffff0000u;
        hi->h[j] = (u16)(h >> 16);
        float r = f[j] - __uint_as_float(h);
        lo->h[j] = (u16)(__float_as_uint(r) >> 16);
    }
}

// 8 floats -> 4 packed dwords hi, 4 packed dwords lo (2 bf16 per dword)
__device__ __forceinline__ void cvt_split8(const float* f, unsigned int* hi,
                                           unsigned int* lo) {
#pragma unroll
    for (int j = 0; j < 4; ++j) {
        unsigned int b0 = __float_as_uint(f[2 * j]);
        unsigned int b1 = __float_as_uint(f[2 * j + 1]);
        unsigned int h0 = b0 & 0xffff0000u;
        unsigned int h1 = b1 & 0xffff0000u;
        hi[j] = (h0 >> 16) | h1;
        float r0 = f[2 * j]     - __uint_as_float(h0);
        float r1 = f[2 * j + 1] - __uint_as_float(h1);
        lo[j] = (__float_as_uint(r0) >> 16) | (__float_as_uint(r1) & 0xffff0000u);
    }
}

// ---------------------------------------------------------------- prep: hist | wprep | xC-split
__global__ __launch_bounds__(256) void k_prep(
    const int* __restrict__ edge, int* __restrict__ cnt, int E, int gE,
    const float* __restrict__ Wl, const float* __restrict__ W0,
    const float* __restrict__ W1, const float* __restrict__ Wout,
    const float* __restrict__ bl, const float* __restrict__ b0,
    const float* __restrict__ b1, const float* __restrict__ gatep,
    const float* __restrict__ xC,
    u16* __restrict__ wlh, u16* __restrict__ wll,
    u16* __restrict__ wch, u16* __restrict__ wcl,
    u16* __restrict__ woh, u16* __restrict__ wol, float* __restrict__ bc,
    u16* __restrict__ xch, u16* __restrict__ xcl, int N)
{
    if (blockIdx.x < (unsigned)gE) {
        int e = blockIdx.x * 256 + threadIdx.x;
        if (e < E) atomicAdd(cnt + edge[E + e], 1);
        return;
    }
    if (blockIdx.x < (unsigned)(gE + 97)) {
        int i = (blockIdx.x - gE) * 256 + threadIdx.x;
        const float g = sigmoid_f(gatep[0]);
        if (i < 16384) {
            int n = i >> 7, k = i & 127;
            float a  = Wl[k * 128 + n];
            float w0 = W0[k * 128 + n];
            float w1 = W1[k * 128 + n];
            float c  = (1.f - g) * w0 + g * w1;
            int off = ((k >> 5) * 128 + n) * 32 + (k & 31);
            split_store(a, wlh + off, wll + off);
            split_store(c, wch + off, wcl + off);
        } else if (i < 24576) {
            int j = i - 16384;
            int n = j >> 7, k = j & 127;
            float v = Wout[k * 64 + n];
            int off = ((k >> 5) * 64 + n) * 32 + (k & 31);
            split_store(v, woh + off, wol + off);
        } else if (i < 24704) {
            int t = i - 24576;
            bc[t] = bl[t] + (1.f - g) * b0[t] + g * b1[t];
        }
        return;
    }
    // xC -> bf16 hi/lo planes, 8 elems/thread
    long long e8 = ((long long)(blockIdx.x - gE - 97) * 256 + threadIdx.x) * 8;
    if (e8 < (long long)N * HD) {
        float4 u0 = *reinterpret_cast<const float4*>(xC + e8);
        float4 u1 = *reinterpret_cast<const float4*>(xC + e8 + 4);
        float f[8] = {u0.x, u0.y, u0.z, u0.w, u1.x, u1.y, u1.z, u1.w};
        Frag hi, lo;
        split_pack8(f, &hi, &lo);
        *reinterpret_cast<uint4*>(xch + e8) = hi.q;
        *reinterpret_cast<uint4*>(xcl + e8) = lo.q;
    }
}

// ---------------------------------------------------------------- scan (1-pass, atomic base)
__global__ __launch_bounds__(256) void k_scan1(
    const int* __restrict__ cnt, int* __restrict__ offs,
    int* __restrict__ part, int* __restrict__ tot, int N)
{
    __shared__ int sh[256];
    const int t = threadIdx.x;
    const int base = blockIdx.x * SCAN_E + t * 4;
    int v[4], sum = 0;
#pragma unroll
    for (int i = 0; i < 4; ++i) {
        int idx = base + i;
        v[i] = (idx < N) ? cnt[idx] : 0;
        sum += v[i];
    }
    sh[t] = sum;
    __syncthreads();
    for (int off = 1; off < 256; off <<= 1) {
        int x = (t >= off) ? sh[t - off] : 0;
        __syncthreads();
        sh[t] += x;
        __syncthreads();
    }
    int run = (t > 0) ? sh[t - 1] : 0;
    if (t == 255) part[blockIdx.x] = atomicAdd(tot, sh[255]);
#pragma unroll
    for (int i = 0; i < 4; ++i) {
        int idx = base + i;
        if (idx < N) offs[idx] = run;
        run += v[i];
    }
}

// ---------------------------------------------------------------- CSR fill + weight
__global__ __launch_bounds__(256) void k_fillw(
    const int* __restrict__ edge, const float* __restrict__ tB,
    const float* __restrict__ tC, const float* __restrict__ lam_raw,
    const int* __restrict__ offs, const int* __restrict__ part,
    int* __restrict__ fillc, int2* __restrict__ srcw, int E)
{
    int e = blockIdx.x * 256 + threadIdx.x;
    if (e >= E) return;
    int s = edge[e];
    int d = edge[E + e];
    float lam = softplus_f(lam_raw[0]) + 1e-8f;
    float dt  = fmaxf(tC[d] - tB[s], 0.0f);
    float w   = expf(fmaxf(-lam * dt, -60.0f));
    int pos = offs[d] + part[d >> 10] + atomicAdd(fillc + d, 1);
    srcw[pos] = make_int2(s, __float_as_int(w));
}

// ---------------------------------------------------------------- gather
// wave per node; 4 edge slots x 16 lanes; lane owns cols l4*8..+7.
// Output: split bf16 hi/lo planes (aggh/aggl).
__global__ __launch_bounds__(256) void k_gather(
    const float* __restrict__ xB, const int2* __restrict__ srcw,
    const int* __restrict__ offs, const int* __restrict__ part,
    const int* __restrict__ cnt, u16* __restrict__ aggh,
    u16* __restrict__ aggl, int N)
{
    const int wave = (blockIdx.x * 256 + threadIdx.x) >> 6;
    const int lane = threadIdx.x & 63;
    const int slot = lane >> 4;
    const int l4   = lane & 15;
    if (wave >= N) return;
    const int r    = wave;
    const int degc = cnt[r];

    if (degc == 0) {
        if (slot == 0) {
            uint4 z = make_uint4(0, 0, 0, 0);
            *reinterpret_cast<uint4*>(aggh + (size_t)r * HD + l4 * 8) = z;
            *reinterpret_cast<uint4*>(aggl + (size_t)r * HD + l4 * 8) = z;
        }
        return;
    }

    const int start = offs[r] + part[r >> 10];
    float4 a0 = make_float4(0, 0, 0, 0), a1 = make_float4(0, 0, 0, 0);
    float sw = 0.f;
#pragma unroll 2
    for (int j = slot; j < degc; j += 4) {
        int2 swp = srcw[start + j];
        float w = __int_as_float(swp.y);
        const float* row = xB + (size_t)swp.x * HD + l4 * 8;
        float4 x0 = *reinterpret_cast<const float4*>(row);
        float4 x1 = *reinterpret_cast<const float4*>(row + 4);
        a0.x = fmaf(w, x0.x, a0.x); a0.y = fmaf(w, x0.y, a0.y);
        a0.z = fmaf(w, x0.z, a0.z); a0.w = fmaf(w, x0.w, a0.w);
        a1.x = fmaf(w, x1.x, a1.x); a1.y = fmaf(w, x1.y, a1.y);
        a1.z = fmaf(w, x1.z, a1.z); a1.w = fmaf(w, x1.w, a1.w);
        sw += w;
    }
#pragma unroll
    for (int m = 16; m <= 32; m <<= 1) {
        a0.x += __shfl_xor(a0.x, m); a0.y += __shfl_xor(a0.y, m);
        a0.z += __shfl_xor(a0.z, m); a0.w += __shfl_xor(a0.w, m);
        a1.x += __shfl_xor(a1.x, m); a1.y += __shfl_xor(a1.y, m);
        a1.z += __shfl_xor(a1.z, m); a1.w += __shfl_xor(a1.w, m);
        sw   += __shfl_xor(sw, m);
    }
    float inv = 1.0f / fmaxf(sw, 1e-6f);
    if (slot == 0) {
        float f[8] = {a0.x * inv, a0.y * inv, a0.z * inv, a0.w * inv,
                      a1.x * inv, a1.y * inv, a1.z * inv, a1.w * inv};
        Frag hi, lo;
        split_pack8(f, &hi, &lo);
        *reinterpret_cast<uint4*>(aggh + (size_t)r * HD + l4 * 8) = hi.q;
        *reinterpret_cast<uint4*>(aggl + (size_t)r * HD + l4 * 8) = lo.q;
    }
}

// ---------------------------------------------------------------- fused K2+K3
// block = 256 thr = 4 waves; block tile = 128 rows x 128 cols.
// Wave wid owns cols [wid*32, wid*32+32).  A chunks (128r x 32k bf16 hi+lo,
// 16KB) staged block-cooperatively via global_load_lds, single-buffered.
// LN via cross-wave partials in LDS; K3 per-32-row group from recycled LDS.
__global__ __launch_bounds__(256) void k_fused(
    const u16* __restrict__ aggh, const u16* __restrict__ aggl,
    const u16* __restrict__ xch, const u16* __restrict__ xcl,
    const int* __restrict__ cnt,
    const u16* __restrict__ wlh, const u16* __restrict__ wll,
    const u16* __restrict__ wch, const u16* __restrict__ wcl,
    const u16* __restrict__ woh, const u16* __restrict__ wol,
    const float* __restrict__ bc, const float* __restrict__ lng,
    const float* __restrict__ lnb, const float* __restrict__ bout,
    float* __restrict__ out, int N)
{
    __shared__ float sm[5120];                 // 20 KB
    u16*   ab16 = (u16*)sm;                    // hi [0..4095], lo [4096..8191]
    float2* pr  = (float2*)&sm[4096];          // 128 rows x 4 waves partials
    float* hc   = sm;                          // 32x128 hC group (post-K2)

    const int tid  = threadIdx.x;
    const int lane = tid & 63;
    const int wid  = tid >> 6;
    const int lr   = lane & 15;
    const int kb   = lane >> 4;
    const int row0 = blockIdx.x * 128;

    const u16* Ah[2] = {aggh, xch};
    const u16* Al[2] = {aggl, xcl};

    v4f acc[8][2] = {};

    // ================= K2: agg@Wl + xC@Wc =================
#pragma unroll
    for (int ch = 0; ch < 8; ++ch) {
        const int mat = ch >> 2, kc = ch & 3;
        // stage 128x32 bf16 chunk (hi+lo), block-cooperative
#pragma unroll
        for (int c = 0; c < 2; ++c) {
            int rowL = c * 64 + (tid >> 2);
            int g    = tid & 3;
            int rG   = row0 + rowL;
            rG = (rG < N) ? rG : (N - 1);
            size_t so = (size_t)rG * HD + kc * 32 + g * 8;
            gload_lds16(Ah[mat] + so, ab16 + c * 2048 + wid * 512);
            gload_lds16(Al[mat] + so, ab16 + 4096 + c * 2048 + wid * 512);
        }
        __syncthreads();   // compiler drains vmcnt before barrier -> data ready

        Frag bh[2], bl[2];
        const uint4* BH = (const uint4*)(mat ? wch : wlh);
        const uint4* BL = (const uint4*)(mat ? wcl : wll);
#pragma unroll
        for (int ct = 0; ct < 2; ++ct) {
            int n   = wid * 32 + ct * 16 + lr;
            int idx = kc * 512 + n * 4 + kb;
            bh[ct].q = BH[idx];
            bl[ct].q = BL[idx];
        }
#pragma unroll
        for (int rt = 0; rt < 8; ++rt) {
            int ro = (rt * 16 + lr) * 32 + kb * 8;
            Frag ah, al;
            ah.q = *reinterpret_cast<const uint4*>(ab16 + ro);
            al.q = *reinterpret_cast<const uint4*>(ab16 + 4096 + ro);
#pragma unroll
            for (int ct = 0; ct < 2; ++ct) {
                acc[rt][ct] = __builtin_amdgcn_mfma_f32_16x16x32_bf16(
                    ah.v, bh[ct].v, acc[rt][ct], 0, 0, 0);
                acc[rt][ct] = __builtin_amdgcn_mfma_f32_16x16x32_bf16(
                    ah.v, bl[ct].v, acc[rt][ct], 0, 0, 0);
                acc[rt][ct] = __builtin_amdgcn_mfma_f32_16x16x32_bf16(
                    al.v, bh[ct].v, acc[rt][ct], 0, 0, 0);
            }
        }
        __syncthreads();   // all reads done before next chunk overwrites
    }

    // ---- per-column constants (2 cols per lane)
    float bcv[2], gav[2], bev[2];
#pragma unroll
    for (int ct = 0; ct < 2; ++ct) {
        int c = wid * 32 + ct * 16 + lr;
        bcv[ct] = bc[c];
        gav[ct] = lng[c];
        bev[ct] = lnb[c];
    }
    const float bov = bout[wid * 16 + lr];

    // ---- LN partials: per-wave 32-col sums -> LDS
#pragma unroll
    for (int rt = 0; rt < 8; ++rt) {
#pragma unroll
        for (int reg = 0; reg < 4; ++reg) {
            float s = 0.f, q = 0.f;
#pragma unroll
            for (int ct = 0; ct < 2; ++ct) {
                float v = fmaxf(acc[rt][ct][reg] + bcv[ct], 0.0f);
                s += v;
                q += v * v;
            }
#pragma unroll
            for (int m = 1; m < 16; m <<= 1) {
                s += __shfl_xor(s, m);
                q += __shfl_xor(q, m);
            }
            if (lr == 0)
                pr[(rt * 16 + kb * 4 + reg) * 4 + wid] = make_float2(s, q);
        }
    }
    __syncthreads();
    // ---- finalize mu/rstd per row
    if (tid < 128) {
        float s = 0.f, q = 0.f;
#pragma unroll
        for (int w = 0; w < 4; ++w) {
            float2 p = pr[tid * 4 + w];
            s += p.x;
            q += p.y;
        }
        float mu  = s * (1.0f / 128.0f);
        float var = q * (1.0f / 128.0f) - mu * mu;
        pr[tid * 4] = make_float2(mu, rsqrtf(var + 1e-5f));
    }
    __syncthreads();

    const uint4* BH3 = (const uint4*)woh;
    const uint4* BL3 = (const uint4*)wol;

    // ======== per 32-row group: epilogue -> hc (LDS) -> K3 -> out ========
#pragma unroll
    for (int rg = 0; rg < 4; ++rg) {
        // epilogue: bias,relu,LN,select -> hc
#pragma unroll
        for (int rt2 = 0; rt2 < 2; ++rt2) {
            const int rt    = rg * 2 + rt2;
            const int lrow0 = rt2 * 16 + kb * 4;
            const int rq    = row0 + rg * 32 + lrow0;
            int cvr[4] = {0, 0, 0, 0};
            if (rq < N) {                    // N%4==0 -> rq+3 < N
                int4 cv = *(const int4*)(cnt + rq);
                cvr[0] = cv.x; cvr[1] = cv.y; cvr[2] = cv.z; cvr[3] = cv.w;
            }
#pragma unroll
            for (int reg = 0; reg < 4; ++reg) {
                const int lrow = lrow0 + reg;
                const int r    = rq + reg;
                float2 mr = pr[(rg * 32 + lrow) * 4];
#pragma unroll
                for (int ct = 0; ct < 2; ++ct) {
                    int col = wid * 32 + ct * 16 + lr;
                    float val = 0.0f;
                    if (r < N) {
                        if (cvr[reg] > 0) {
                            float y = fmaxf(acc[rt][ct][reg] + bcv[ct], 0.0f);
                            val = (y - mr.x) * mr.y * gav[ct] + bev[ct];
                        } else {
                            size_t xo = (size_t)r * HD + col;
                            unsigned int hb = ((unsigned int)xch[xo]) << 16;
                            unsigned int lb = ((unsigned int)xcl[xo]) << 16;
                            val = __uint_as_float(hb) + __uint_as_float(lb);
                        }
                    }
                    hc[swz(lrow, col)] = val;
                }
            }
        }
        __syncthreads();

        // K3 on these 32 rows; wave owns out-cols wid*16..+15
        v4f acc2[2] = {};
#pragma unroll
        for (int kcc = 0; kcc < 4; ++kcc) {
            Frag b3h, b3l;
            {
                int n   = wid * 16 + lr;
                int idx = kcc * 256 + n * 4 + kb;
                b3h.q = BH3[idx];
                b3l.q = BL3[idx];
            }
#pragma unroll
            for (int rt3 = 0; rt3 < 2; ++rt3) {
                int rr = rt3 * 16 + lr;
                int c0 = kcc * 32 + kb * 8;
                float4 u0 = *reinterpret_cast<const float4*>(&hc[swz(rr, c0)]);
                float4 u1 = *reinterpret_cast<const float4*>(&hc[swz(rr, c0 + 4)]);
                float f[8] = {u0.x, u0.y, u0.z, u0.w, u1.x, u1.y, u1.z, u1.w};
                Frag ah, al;
                cvt_split8(f, ah.u, al.u);
                acc2[rt3] = __builtin_amdgcn_mfma_f32_16x16x32_bf16(
                    ah.v, b3h.v, acc2[rt3], 0, 0, 0);
                acc2[rt3] = __builtin_amdgcn_mfma_f32_16x16x32_bf16(
                    ah.v, b3l.v, acc2[rt3], 0, 0, 0);
                acc2[rt3] = __builtin_amdgcn_mfma_f32_16x16x32_bf16(
                    al.v, b3h.v, acc2[rt3], 0, 0, 0);
            }
        }
#pragma unroll
        for (int rt3 = 0; rt3 < 2; ++rt3) {
#pragma unroll
            for (int reg = 0; reg < 4; ++reg) {
                int r = row0 + rg * 32 + rt3 * 16 + kb * 4 + reg;
                if (r < N)
                    out[(size_t)r * OD + wid * 16 + lr] = acc2[rt3][reg] + bov;
            }
        }
        __syncthreads();   // before next group overwrites hc
    }
}

// ---------------------------------------------------------------- launch
extern "C" void kernel_launch(void* const* d_in, const int* in_sizes, int n_in,
                              void* d_out, int out_size, void* d_ws, size_t ws_size,
                              hipStream_t stream) {
    const float* xB    = (const float*)d_in[1];
    const float* xC    = (const float*)d_in[2];
    const float* tB    = (const float*)d_in[4];
    const float* tC    = (const float*)d_in[5];
    const int*   edge2 = (const int*)d_in[7];
    const float* Wl1   = (const float*)d_in[18];
    const float* bl1   = (const float*)d_in[19];
    const float* W01   = (const float*)d_in[20];
    const float* b01   = (const float*)d_in[21];
    const float* W11   = (const float*)d_in[22];
    const float* b11   = (const float*)d_in[23];
    const float* gate1 = (const float*)d_in[24];
    const float* lam1  = (const float*)d_in[25];
    const float* lng1  = (const float*)d_in[26];
    const float* lnb1  = (const float*)d_in[27];
    const float* Wout  = (const float*)d_in[28];
    const float* bout  = (const float*)d_in[29];

    const int N = in_sizes[2] / HD;
    const int E = in_sizes[7] / 2;

    int*   cnt   = (int*)d_ws;
    int*   fillc = cnt + N;
    int*   offs  = fillc + N;
    int*   part  = offs + N;
    int*   tot   = part + 128;
    int2*  srcw  = (int2*)(tot + 4);
    u16*   wlh   = (u16*)(srcw + E);
    u16*   wll   = wlh + 16384;
    u16*   wch   = wll + 16384;
    u16*   wcl   = wch + 16384;
    u16*   woh   = wcl + 16384;
    u16*   wol   = woh + 8192;
    float* bc    = (float*)(wol + 8192);
    u16*   aggh  = (u16*)(bc + 128);
    u16*   aggl  = aggh + (size_t)N * HD;
    u16*   xch   = aggl + (size_t)N * HD;
    u16*   xcl   = xch + (size_t)N * HD;

    hipMemsetAsync(cnt, 0, (size_t)2 * N * sizeof(int), stream);
    hipMemsetAsync(tot, 0, sizeof(int), stream);

    dim3 blk(256);
    const int gE = (E + 255) / 256;
    const int NB = (N + SCAN_E - 1) / SCAN_E;
    const int gX = (N * (HD / 8) + 255) / 256;   // xC-split blocks

    k_prep <<<gE + 97 + gX, blk, 0, stream>>>(edge2, cnt, E, gE,
                                              Wl1, W01, W11, Wout, bl1, b01, b11,
                                              gate1, xC, wlh, wll, wch, wcl,
                                              woh, wol, bc, xch, xcl, N);
    k_scan1<<<NB, blk, 0, stream>>>(cnt, offs, part, tot, N);
    k_fillw<<<gE, blk, 0, stream>>>(edge2, tB, tC, lam1, offs, part, fillc, srcw, E);

    const int gN64 = (N * 64 + 255) / 256;
    k_gather<<<gN64, blk, 0, stream>>>(xB, srcw, offs, part, cnt, aggh, aggl, N);

    const int GB = (N + 127) / 128;
    k_fused<<<GB, blk, 0, stream>>>(aggh, aggl, xch, xcl, cnt,
                                    wlh, wll, wch, wcl, woh, wol,
                                    bc, lng1, lnb1, bout, (float*)d_out, N);
}

// Round 17
// 240.013 us; speedup vs baseline: 1.1675x; 1.1675x over previous
//
#include <hip/hip_runtime.h>

// MetaPathGNN — only the edge2 (B->C) layer + output GEMM matter.
//
// R16 (resubmit; source unchanged — UnresponsiveContainer infra failure,
// never executed): k_fused = wave-private counted-vmcnt pipeline.
//  - A (aggh/aggl, xch/xcl bf16 planes) staged per-wave in FRAG ORDER via
//    global_load_lds: per-lane pre-permuted global source, linear LDS dest,
//    so ds_read_b128 at lane*16 is conflict-free.  4 gloads / 4KB chunk.
//  - Double-buffer + s_waitcnt vmcnt(4) (vmcnt(0) only for the last chunk):
//    next chunk's loads stay in flight across compute (R14's vmcnt(0)-drain
//    and R15's barrier serialization both removed; zero __syncthreads).
//  - K2 A-frags raw bf16 -> no cvt VALU.  Geometry: 128 rows/block,
//    wave = 32 rows x 128 cols (R11's best-measured).
//
// ws (ints): [cnt N | fillc N | offs N | part 128 | tot 4 | srcw 2E |
//             wlh/wll/wch/wcl 16384u16 | woh/wol 8192u16 | bc 128f |
//             aggh | aggl | xch | xcl (each N*128 u16)]

#define HD 128
#define OD 64
#define SCAN_E 1024

typedef unsigned short u16;
typedef short v8s __attribute__((ext_vector_type(8)));
typedef float v4f __attribute__((ext_vector_type(4)));

union Frag {
    unsigned int u[4];
    uint4 q;
    v8s v;
    u16 h[8];
};

__device__ __forceinline__ float softplus_f(float x) {
    return fmaxf(x, 0.0f) + log1pf(expf(-fabsf(x)));
}
__device__ __forceinline__ float sigmoid_f(float x) {
    return 1.0f / (1.0f + expf(-x));
}
// swizzled LDS offset within a [16][128] fp32 slice: 16B granule XOR row&7
__device__ __forceinline__ int swz(int r, int c) {
    int g = (c >> 2) ^ (r & 7);
    return r * 128 + g * 4 + (c & 3);
}

// async 16B global->LDS (lds dest wave-uniform; HW puts lane i at dest+i*16)
__device__ __forceinline__ void gload_lds16(const void* g, void* l) {
    __builtin_amdgcn_global_load_lds(
        (const __attribute__((address_space(1))) void*)g,
        (__attribute__((address_space(3))) void*)l, 16, 0, 0);
}

// split x into bf16 hi + bf16 lo (truncation split; residual ~2^-17 |x|)
__device__ __forceinline__ void split_store(float x, u16* ph, u16* pl) {
    unsigned int b = __float_as_uint(x);
    unsigned int h = b & 0xffff0000u;
    *ph = (u16)(h >> 16);
    float r = x - __uint_as_float(h);
    *pl = (u16)(__float_as_uint(r) >> 16);
}

// 8 floats -> ushort8 hi plane + ushort8 lo plane
__device__ __forceinline__ void split_pack8(const float* f, Frag* hi, Frag* lo) {
#pragma unroll
    for (int j = 0; j < 8; ++j) {
        unsigned int b = __float_as_uint(f[j]);
        unsigned int h = b & 0xffff0000u;
        hi->h[j] = (u16)(h >> 16);
        float r = f[j] - __uint_as_float(h);
        lo->h[j] = (u16)(__float_as_uint(r) >> 16);
    }
}

// 8 floats -> 4 packed dwords hi, 4 packed dwords lo (2 bf16 per dword)
__device__ __forceinline__ void cvt_split8(const float* f, unsigned int* hi,
                                           unsigned int* lo) {
#pragma unroll
    for (int j = 0; j < 4; ++j) {
        unsigned int b0 = __float_as_uint(f[2 * j]);
        unsigned int b1 = __float_as_uint(f[2 * j + 1]);
        unsigned int h0 = b0 & 0xffff0000u;
        unsigned int h1 = b1 & 0xffff0000u;
        hi[j] = (h0 >> 16) | h1;
        float r0 = f[2 * j]     - __uint_as_float(h0);
        float r1 = f[2 * j + 1] - __uint_as_float(h1);
        lo[j] = (__float_as_uint(r0) >> 16) | (__float_as_uint(r1) & 0xffff0000u);
    }
}

// stage one chunk (32 rows x 32 k, bf16 hi+lo = 4KB) in FRAG ORDER:
// lane l sources A[row0w + rt*16 + (l&15)][kc*32 + (l>>4)*8 ..+7]; HW writes
// it at buf + plane*2048 + rt*1024 + l*16 — exactly where the reader wants it.
__device__ __forceinline__ void stage_chunk(
    const u16* __restrict__ Ah, const u16* __restrict__ Al,
    int kc, char* buf, int row0w, int lane, int N)
{
    const int rfrag = lane & 15;
    const int kb    = lane >> 4;
#pragma unroll
    for (int rt = 0; rt < 2; ++rt) {
        int rG = row0w + rt * 16 + rfrag;
        rG = (rG < N) ? rG : (N - 1);
        size_t so = (size_t)rG * HD + kc * 32 + kb * 8;
        gload_lds16(Ah + so, buf + rt * 1024);
        gload_lds16(Al + so, buf + 2048 + rt * 1024);
    }
}

// ---------------------------------------------------------------- prep: hist | wprep | xC-split
__global__ __launch_bounds__(256) void k_prep(
    const int* __restrict__ edge, int* __restrict__ cnt, int E, int gE,
    const float* __restrict__ Wl, const float* __restrict__ W0,
    const float* __restrict__ W1, const float* __restrict__ Wout,
    const float* __restrict__ bl, const float* __restrict__ b0,
    const float* __restrict__ b1, const float* __restrict__ gatep,
    const float* __restrict__ xC,
    u16* __restrict__ wlh, u16* __restrict__ wll,
    u16* __restrict__ wch, u16* __restrict__ wcl,
    u16* __restrict__ woh, u16* __restrict__ wol, float* __restrict__ bc,
    u16* __restrict__ xch, u16* __restrict__ xcl, int N)
{
    if (blockIdx.x < (unsigned)gE) {
        int e = blockIdx.x * 256 + threadIdx.x;
        if (e < E) atomicAdd(cnt + edge[E + e], 1);
        return;
    }
    if (blockIdx.x < (unsigned)(gE + 97)) {
        int i = (blockIdx.x - gE) * 256 + threadIdx.x;
        const float g = sigmoid_f(gatep[0]);
        if (i < 16384) {
            int n = i >> 7, k = i & 127;
            float a  = Wl[k * 128 + n];
            float w0 = W0[k * 128 + n];
            float w1 = W1[k * 128 + n];
            float c  = (1.f - g) * w0 + g * w1;
            int off = ((k >> 5) * 128 + n) * 32 + (k & 31);
            split_store(a, wlh + off, wll + off);
            split_store(c, wch + off, wcl + off);
        } else if (i < 24576) {
            int j = i - 16384;
            int n = j >> 7, k = j & 127;
            float v = Wout[k * 64 + n];
            int off = ((k >> 5) * 64 + n) * 32 + (k & 31);
            split_store(v, woh + off, wol + off);
        } else if (i < 24704) {
            int t = i - 24576;
            bc[t] = bl[t] + (1.f - g) * b0[t] + g * b1[t];
        }
        return;
    }
    long long e8 = ((long long)(blockIdx.x - gE - 97) * 256 + threadIdx.x) * 8;
    if (e8 < (long long)N * HD) {
        float4 u0 = *reinterpret_cast<const float4*>(xC + e8);
        float4 u1 = *reinterpret_cast<const float4*>(xC + e8 + 4);
        float f[8] = {u0.x, u0.y, u0.z, u0.w, u1.x, u1.y, u1.z, u1.w};
        Frag hi, lo;
        split_pack8(f, &hi, &lo);
        *reinterpret_cast<uint4*>(xch + e8) = hi.q;
        *reinterpret_cast<uint4*>(xcl + e8) = lo.q;
    }
}

// ---------------------------------------------------------------- scan (1-pass, atomic base)
__global__ __launch_bounds__(256) void k_scan1(
    const int* __restrict__ cnt, int* __restrict__ offs,
    int* __restrict__ part, int* __restrict__ tot, int N)
{
    __shared__ int sh[256];
    const int t = threadIdx.x;
    const int base = blockIdx.x * SCAN_E + t * 4;
    int v[4], sum = 0;
#pragma unroll
    for (int i = 0; i < 4; ++i) {
        int idx = base + i;
        v[i] = (idx < N) ? cnt[idx] : 0;
        sum += v[i];
    }
    sh[t] = sum;
    __syncthreads();
    for (int off = 1; off < 256; off <<= 1) {
        int x = (t >= off) ? sh[t - off] : 0;
        __syncthreads();
        sh[t] += x;
        __syncthreads();
    }
    int run = (t > 0) ? sh[t - 1] : 0;
    if (t == 255) part[blockIdx.x] = atomicAdd(tot, sh[255]);
#pragma unroll
    for (int i = 0; i < 4; ++i) {
        int idx = base + i;
        if (idx < N) offs[idx] = run;
        run += v[i];
    }
}

// ---------------------------------------------------------------- CSR fill + weight
__global__ __launch_bounds__(256) void k_fillw(
    const int* __restrict__ edge, const float* __restrict__ tB,
    const float* __restrict__ tC, const float* __restrict__ lam_raw,
    const int* __restrict__ offs, const int* __restrict__ part,
    int* __restrict__ fillc, int2* __restrict__ srcw, int E)
{
    int e = blockIdx.x * 256 + threadIdx.x;
    if (e >= E) return;
    int s = edge[e];
    int d = edge[E + e];
    float lam = softplus_f(lam_raw[0]) + 1e-8f;
    float dt  = fmaxf(tC[d] - tB[s], 0.0f);
    float w   = expf(fmaxf(-lam * dt, -60.0f));
    int pos = offs[d] + part[d >> 10] + atomicAdd(fillc + d, 1);
    srcw[pos] = make_int2(s, __float_as_int(w));
}

// ---------------------------------------------------------------- gather
// wave per node; 4 edge slots x 16 lanes; lane owns cols l4*8..+7.
// Output: split bf16 hi/lo planes (aggh/aggl).
__global__ __launch_bounds__(256) void k_gather(
    const float* __restrict__ xB, const int2* __restrict__ srcw,
    const int* __restrict__ offs, const int* __restrict__ part,
    const int* __restrict__ cnt, u16* __restrict__ aggh,
    u16* __restrict__ aggl, int N)
{
    const int wave = (blockIdx.x * 256 + threadIdx.x) >> 6;
    const int lane = threadIdx.x & 63;
    const int slot = lane >> 4;
    const int l4   = lane & 15;
    if (wave >= N) return;
    const int r    = wave;
    const int degc = cnt[r];

    if (degc == 0) {
        if (slot == 0) {
            uint4 z = make_uint4(0, 0, 0, 0);
            *reinterpret_cast<uint4*>(aggh + (size_t)r * HD + l4 * 8) = z;
            *reinterpret_cast<uint4*>(aggl + (size_t)r * HD + l4 * 8) = z;
        }
        return;
    }

    const int start = offs[r] + part[r >> 10];
    float4 a0 = make_float4(0, 0, 0, 0), a1 = make_float4(0, 0, 0, 0);
    float sw = 0.f;
#pragma unroll 2
    for (int j = slot; j < degc; j += 4) {
        int2 swp = srcw[start + j];
        float w = __int_as_float(swp.y);
        const float* row = xB + (size_t)swp.x * HD + l4 * 8;
        float4 x0 = *reinterpret_cast<const float4*>(row);
        float4 x1 = *reinterpret_cast<const float4*>(row + 4);
        a0.x = fmaf(w, x0.x, a0.x); a0.y = fmaf(w, x0.y, a0.y);
        a0.z = fmaf(w, x0.z, a0.z); a0.w = fmaf(w, x0.w, a0.w);
        a1.x = fmaf(w, x1.x, a1.x); a1.y = fmaf(w, x1.y, a1.y);
        a1.z = fmaf(w, x1.z, a1.z); a1.w = fmaf(w, x1.w, a1.w);
        sw += w;
    }
#pragma unroll
    for (int m = 16; m <= 32; m <<= 1) {
        a0.x += __shfl_xor(a0.x, m); a0.y += __shfl_xor(a0.y, m);
        a0.z += __shfl_xor(a0.z, m); a0.w += __shfl_xor(a0.w, m);
        a1.x += __shfl_xor(a1.x, m); a1.y += __shfl_xor(a1.y, m);
        a1.z += __shfl_xor(a1.z, m); a1.w += __shfl_xor(a1.w, m);
        sw   += __shfl_xor(sw, m);
    }
    float inv = 1.0f / fmaxf(sw, 1e-6f);
    if (slot == 0) {
        float f[8] = {a0.x * inv, a0.y * inv, a0.z * inv, a0.w * inv,
                      a1.x * inv, a1.y * inv, a1.z * inv, a1.w * inv};
        Frag hi, lo;
        split_pack8(f, &hi, &lo);
        *reinterpret_cast<uint4*>(aggh + (size_t)r * HD + l4 * 8) = hi.q;
        *reinterpret_cast<uint4*>(aggl + (size_t)r * HD + l4 * 8) = lo.q;
    }
}

// ---------------------------------------------------------------- fused K2+K3
// block = 256 thr = 4 waves; wave owns 32 rows x 128 cols + 8KB LDS slice.
// K2: counted-vmcnt double-buffered frag-order A staging; B from L2 planes.
// Then per 16-row tile: epilogue -> slice (recycled stage bufs) -> K3 -> out.
__global__ __launch_bounds__(256) void k_fused(
    const u16* __restrict__ aggh, const u16* __restrict__ aggl,
    const u16* __restrict__ xch, const u16* __restrict__ xcl,
    const float* __restrict__ xC, const int* __restrict__ cnt,
    const u16* __restrict__ wlh, const u16* __restrict__ wll,
    const u16* __restrict__ wch, const u16* __restrict__ wcl,
    const u16* __restrict__ woh, const u16* __restrict__ wol,
    const float* __restrict__ bc, const float* __restrict__ lng,
    const float* __restrict__ lnb, const float* __restrict__ bout,
    float* __restrict__ out, int N)
{
    __shared__ char lds[32768];        // 4 waves x 8KB (2 x 4KB stage bufs)

    const int lane = threadIdx.x & 63;
    const int wid  = threadIdx.x >> 6;
    const int lr   = lane & 15;        // frag row (A) / col (B/C)
    const int kb   = lane >> 4;        // k-block 0..3
    const int row0 = blockIdx.x * 128 + wid * 32;
    char* myb = lds + wid * 8192;
    char* bufs[2] = {myb, myb + 4096};

    const u16* Ahp[2] = {aggh, xch};
    const u16* Alp[2] = {aggl, xcl};

    v4f acc[2][8] = {};

    // ================= K2: agg@Wl + xC@Wc (pipelined) =================
    stage_chunk(Ahp[0], Alp[0], 0, bufs[0], row0, lane, N);
    stage_chunk(Ahp[0], Alp[0], 1, bufs[1], row0, lane, N);

#pragma unroll
    for (int ch = 0; ch < 8; ++ch) {
        const int mat = ch >> 2, kc = ch & 3;
        if (ch == 7) {
            asm volatile("s_waitcnt vmcnt(0)" ::: "memory");
        } else {
            asm volatile("s_waitcnt vmcnt(4)" ::: "memory");
        }
        const char* cb = bufs[ch & 1];

        // A frags: fully linear ds_read_b128 at lane*16 (conflict-free)
        Frag ah[2], al[2];
#pragma unroll
        for (int rt = 0; rt < 2; ++rt) {
            ah[rt].q = *reinterpret_cast<const uint4*>(cb + rt * 1024 + lane * 16);
            al[rt].q = *reinterpret_cast<const uint4*>(cb + 2048 + rt * 1024 + lane * 16);
        }
        asm volatile("s_waitcnt lgkmcnt(0)" ::: "memory");
        __builtin_amdgcn_sched_barrier(0);

        // prefetch chunk ch+2 into the buffer we just finished reading
        if (ch + 2 < 8) {
            const int nc = ch + 2;
            stage_chunk(Ahp[nc >> 2], Alp[nc >> 2], nc & 3,
                        bufs[ch & 1], row0, lane, N);
        }

        const uint4* BH = (const uint4*)(mat ? wch : wlh);
        const uint4* BL = (const uint4*)(mat ? wcl : wll);
#pragma unroll
        for (int ct = 0; ct < 8; ++ct) {
            int idx = kc * 512 + (ct * 16 + lr) * 4 + kb;
            Frag bh, bl;
            bh.q = BH[idx];
            bl.q = BL[idx];
#pragma unroll
            for (int rt = 0; rt < 2; ++rt) {
                acc[rt][ct] = __builtin_amdgcn_mfma_f32_16x16x32_bf16(
                    ah[rt].v, bh.v, acc[rt][ct], 0, 0, 0);
                acc[rt][ct] = __builtin_amdgcn_mfma_f32_16x16x32_bf16(
                    ah[rt].v, bl.v, acc[rt][ct], 0, 0, 0);
                acc[rt][ct] = __builtin_amdgcn_mfma_f32_16x16x32_bf16(
                    al[rt].v, bh.v, acc[rt][ct], 0, 0, 0);
            }
        }
    }

    // ---- per-column constants
    float bcv[8], gav[8], bev[8];
#pragma unroll
    for (int ct = 0; ct < 8; ++ct) {
        int c = ct * 16 + lr;
        bcv[ct] = bc[c];
        gav[ct] = lng[c];
        bev[ct] = lnb[c];
    }
    float bov[4];
#pragma unroll
    for (int ct = 0; ct < 4; ++ct) bov[ct] = bout[ct * 16 + lr];

    const uint4* BH3 = (const uint4*)woh;
    const uint4* BL3 = (const uint4*)wol;
    float* hc = (float*)myb;           // 16x128 fp32 slice (8KB, recycled)

    // ======== per 16-row tile: epilogue -> slice -> K3 -> out ========
#pragma unroll
    for (int rt = 0; rt < 2; ++rt) {
        int rq = row0 + rt * 16 + kb * 4;    // first of this lane's 4 rows
        int cvr[4] = {0, 0, 0, 0};
        if (rq < N) {                        // N%4==0, rq%4==0 -> rq+3 < N
            int4 cv = *(const int4*)(cnt + rq);
            cvr[0] = cv.x; cvr[1] = cv.y; cvr[2] = cv.z; cvr[3] = cv.w;
        }
#pragma unroll
        for (int reg = 0; reg < 4; ++reg) {
            int rloc = kb * 4 + reg;         // 0..15 within the tile
            int r    = rq + reg;
            float yv[8];
            float s = 0.f, q = 0.f;
#pragma unroll
            for (int ct = 0; ct < 8; ++ct) {
                float v = acc[rt][ct][reg] + bcv[ct];
                v = fmaxf(v, 0.0f);
                yv[ct] = v;
                s += v;
                q += v * v;
            }
#pragma unroll
            for (int m = 1; m < 16; m <<= 1) {
                s += __shfl_xor(s, m);
                q += __shfl_xor(q, m);
            }
            float mu   = s * (1.0f / 128.0f);
            float var  = q * (1.0f / 128.0f) - mu * mu;
            float rstd = rsqrtf(var + 1e-5f);

            if (r < N) {
                if (cvr[reg] > 0) {
#pragma unroll
                    for (int ct = 0; ct < 8; ++ct)
                        hc[swz(rloc, ct * 16 + lr)] =
                            (yv[ct] - mu) * rstd * gav[ct] + bev[ct];
                } else {
                    size_t base = (size_t)r * HD;
#pragma unroll
                    for (int ct = 0; ct < 8; ++ct)
                        hc[swz(rloc, ct * 16 + lr)] = xC[base + ct * 16 + lr];
                }
            } else {
#pragma unroll
                for (int ct = 0; ct < 8; ++ct)
                    hc[swz(rloc, ct * 16 + lr)] = 0.0f;
            }
        }
        // wave-private slice; same-wave DS ordering is in-order

        // ---- K3 on this 16-row tile
        v4f acc2[4] = {};
#pragma unroll
        for (int kc = 0; kc < 4; ++kc) {
            Frag ah, al;
            {
                int c0 = kc * 32 + kb * 8;
                float4 u0 = *reinterpret_cast<const float4*>(&hc[swz(lr, c0)]);
                float4 u1 = *reinterpret_cast<const float4*>(&hc[swz(lr, c0 + 4)]);
                float f[8] = {u0.x, u0.y, u0.z, u0.w, u1.x, u1.y, u1.z, u1.w};
                cvt_split8(f, ah.u, al.u);
            }
#pragma unroll
            for (int ct = 0; ct < 4; ++ct) {
                int idx = kc * 256 + (ct * 16 + lr) * 4 + kb;
                Frag bh, bl;
                bh.q = BH3[idx];
                bl.q = BL3[idx];
                acc2[ct] = __builtin_amdgcn_mfma_f32_16x16x32_bf16(
                    ah.v, bh.v, acc2[ct], 0, 0, 0);
                acc2[ct] = __builtin_amdgcn_mfma_f32_16x16x32_bf16(
                    ah.v, bl.v, acc2[ct], 0, 0, 0);
                acc2[ct] = __builtin_amdgcn_mfma_f32_16x16x32_bf16(
                    al.v, bh.v, acc2[ct], 0, 0, 0);
            }
        }

#pragma unroll
        for (int reg = 0; reg < 4; ++reg) {
            int r = rq + reg;
            if (r < N) {
#pragma unroll
                for (int ct = 0; ct < 4; ++ct)
                    out[(size_t)r * OD + ct * 16 + lr] = acc2[ct][reg] + bov[ct];
            }
        }
    }
}

// ---------------------------------------------------------------- launch
extern "C" void kernel_launch(void* const* d_in, const int* in_sizes, int n_in,
                              void* d_out, int out_size, void* d_ws, size_t ws_size,
                              hipStream_t stream) {
    const float* xB    = (const float*)d_in[1];
    const float* xC    = (const float*)d_in[2];
    const float* tB    = (const float*)d_in[4];
    const float* tC    = (const float*)d_in[5];
    const int*   edge2 = (const int*)d_in[7];
    const float* Wl1   = (const float*)d_in[18];
    const float* bl1   = (const float*)d_in[19];
    const float* W01   = (const float*)d_in[20];
    const float* b01   = (const float*)d_in[21];
    const float* W11   = (const float*)d_in[22];
    const float* b11   = (const float*)d_in[23];
    const float* gate1 = (const float*)d_in[24];
    const float* lam1  = (const float*)d_in[25];
    const float* lng1  = (const float*)d_in[26];
    const float* lnb1  = (const float*)d_in[27];
    const float* Wout  = (const float*)d_in[28];
    const float* bout  = (const float*)d_in[29];

    const int N = in_sizes[2] / HD;
    const int E = in_sizes[7] / 2;

    int*   cnt   = (int*)d_ws;
    int*   fillc = cnt + N;
    int*   offs  = fillc + N;
    int*   part  = offs + N;
    int*   tot   = part + 128;
    int2*  srcw  = (int2*)(tot + 4);
    u16*   wlh   = (u16*)(srcw + E);
    u16*   wll   = wlh + 16384;
    u16*   wch   = wll + 16384;
    u16*   wcl   = wch + 16384;
    u16*   woh   = wcl + 16384;
    u16*   wol   = woh + 8192;
    float* bc    = (float*)(wol + 8192);
    u16*   aggh  = (u16*)(bc + 128);
    u16*   aggl  = aggh + (size_t)N * HD;
    u16*   xch   = aggl + (size_t)N * HD;
    u16*   xcl   = xch + (size_t)N * HD;

    hipMemsetAsync(cnt, 0, (size_t)2 * N * sizeof(int), stream);
    hipMemsetAsync(tot, 0, sizeof(int), stream);

    dim3 blk(256);
    const int gE = (E + 255) / 256;
    const int NB = (N + SCAN_E - 1) / SCAN_E;
    const int gX = (N * (HD / 8) + 255) / 256;   // xC-split blocks

    k_prep <<<gE + 97 + gX, blk, 0, stream>>>(edge2, cnt, E, gE,
                                              Wl1, W01, W11, Wout, bl1, b01, b11,
                                              gate1, xC, wlh, wll, wch, wcl,
                                              woh, wol, bc, xch, xcl, N);
    k_scan1<<<NB, blk, 0, stream>>>(cnt, offs, part, tot, N);
    k_fillw<<<gE, blk, 0, stream>>>(edge2, tB, tC, lam1, offs, part, fillc, srcw, E);

    const int gN64 = (N * 64 + 255) / 256;
    k_gather<<<gN64, blk, 0, stream>>>(xB, srcw, offs, part, cnt, aggh, aggl, N);

    const int GB = (N + 127) / 128;
    k_fused<<<GB, blk, 0, stream>>>(aggh, aggl, xch, xcl, xC, cnt,
                                    wlh, wll, wch, wcl, woh, wol,
                                    bc, lng1, lnb1, bout, (float*)d_out, N);
}

// Round 18
// 238.038 us; speedup vs baseline: 1.1772x; 1.0083x over previous
//
#include <hip/hip_runtime.h>

// MetaPathGNN — only the edge2 (B->C) layer + output GEMM matter.
//
// R18: (1) gather edge-skip: per-node wmax (atomicMax in fillw); edges with
//      w < wmax*1e-8 contribute <1e-7 relative — skip their 512B row read
//      (~half the edges: w=e^-60 floor vs w=1 cluster).
//      (2) k_fused: B planes staged block-cooperatively into LDS (dbuf,
//      counted vmcnt(8), raw s_barrier — no __syncthreads vmcnt-drain),
//      killing the 4x per-wave B L2 redundancy (640->128 KB/block).  K3's
//      woh/wol staged once into the freed region.  A staging = R16 (proven).
//
// ws (ints): [cnt N | fillc N | wmax N | offs N | part 128 | tot 4 | srcw 2E |
//             wlh/wll/wch/wcl 16384u16 | woh/wol 8192u16 | bc 128f |
//             aggh | aggl | xch | xcl (each N*128 u16)]

#define HD 128
#define OD 64
#define SCAN_E 1024

typedef unsigned short u16;
typedef short v8s __attribute__((ext_vector_type(8)));
typedef float v4f __attribute__((ext_vector_type(4)));

union Frag {
    unsigned int u[4];
    uint4 q;
    v8s v;
    u16 h[8];
};

__device__ __forceinline__ float softplus_f(float x) {
    return fmaxf(x, 0.0f) + log1pf(expf(-fabsf(x)));
}
__device__ __forceinline__ float sigmoid_f(float x) {
    return 1.0f / (1.0f + expf(-x));
}
// swizzled LDS offset within a [16][128] fp32 slice: 16B granule XOR row&7
__device__ __forceinline__ int swz(int r, int c) {
    int g = (c >> 2) ^ (r & 7);
    return r * 128 + g * 4 + (c & 3);
}

// async 16B global->LDS (lds dest wave-uniform; HW puts lane i at dest+i*16)
__device__ __forceinline__ void gload_lds16(const void* g, void* l) {
    __builtin_amdgcn_global_load_lds(
        (const __attribute__((address_space(1))) void*)g,
        (__attribute__((address_space(3))) void*)l, 16, 0, 0);
}

__device__ __forceinline__ void split_store(float x, u16* ph, u16* pl) {
    unsigned int b = __float_as_uint(x);
    unsigned int h = b & 0xffff0000u;
    *ph = (u16)(h >> 16);
    float r = x - __uint_as_float(h);
    *pl = (u16)(__float_as_uint(r) >> 16);
}

__device__ __forceinline__ void split_pack8(const float* f, Frag* hi, Frag* lo) {
#pragma unroll
    for (int j = 0; j < 8; ++j) {
        unsigned int b = __float_as_uint(f[j]);
        unsigned int h = b & 0xffff0000u;
        hi->h[j] = (u16)(h >> 16);
        float r = f[j] - __uint_as_float(h);
        lo->h[j] = (u16)(__float_as_uint(r) >> 16);
    }
}

__device__ __forceinline__ void cvt_split8(const float* f, unsigned int* hi,
                                           unsigned int* lo) {
#pragma unroll
    for (int j = 0; j < 4; ++j) {
        unsigned int b0 = __float_as_uint(f[2 * j]);
        unsigned int b1 = __float_as_uint(f[2 * j + 1]);
        unsigned int h0 = b0 & 0xffff0000u;
        unsigned int h1 = b1 & 0xffff0000u;
        hi[j] = (h0 >> 16) | h1;
        float r0 = f[2 * j]     - __uint_as_float(h0);
        float r1 = f[2 * j + 1] - __uint_as_float(h1);
        lo[j] = (__float_as_uint(r0) >> 16) | (__float_as_uint(r1) & 0xffff0000u);
    }
}

// A chunk (32 rows x 32 k bf16 hi+lo = 4KB) per-wave in FRAG ORDER (R16)
__device__ __forceinline__ void stage_A(
    const u16* __restrict__ Ah, const u16* __restrict__ Al,
    int kc, char* buf, int row0w, int lane, int N)
{
    const int rfrag = lane & 15;
    const int kb    = lane >> 4;
#pragma unroll
    for (int rt = 0; rt < 2; ++rt) {
        int rG = row0w + rt * 16 + rfrag;
        rG = (rG < N) ? rG : (N - 1);
        size_t so = (size_t)rG * HD + kc * 32 + kb * 8;
        gload_lds16(Ah + so, buf + rt * 1024);
        gload_lds16(Al + so, buf + 2048 + rt * 1024);
    }
}

// B chunk (128 n x 32 k bf16 hi+lo = 16KB) block-cooperative, linear copy
__device__ __forceinline__ void stage_B(
    const u16* __restrict__ Bh, const u16* __restrict__ Bl,
    int kc, char* bbuf, int wid, int lane)
{
#pragma unroll
    for (int i = 0; i < 2; ++i) {
        int seg = wid * 2 + i;
        gload_lds16((const char*)Bh + kc * 8192 + seg * 1024 + lane * 16,
                    bbuf + seg * 1024);
        gload_lds16((const char*)Bl + kc * 8192 + seg * 1024 + lane * 16,
                    bbuf + 8192 + seg * 1024);
    }
}

// ---------------------------------------------------------------- prep
__global__ __launch_bounds__(256) void k_prep(
    const int* __restrict__ edge, int* __restrict__ cnt, int E, int gE,
    const float* __restrict__ Wl, const float* __restrict__ W0,
    const float* __restrict__ W1, const float* __restrict__ Wout,
    const float* __restrict__ bl, const float* __restrict__ b0,
    const float* __restrict__ b1, const float* __restrict__ gatep,
    const float* __restrict__ xC,
    u16* __restrict__ wlh, u16* __restrict__ wll,
    u16* __restrict__ wch, u16* __restrict__ wcl,
    u16* __restrict__ woh, u16* __restrict__ wol, float* __restrict__ bc,
    u16* __restrict__ xch, u16* __restrict__ xcl, int N)
{
    if (blockIdx.x < (unsigned)gE) {
        int e = blockIdx.x * 256 + threadIdx.x;
        if (e < E) atomicAdd(cnt + edge[E + e], 1);
        return;
    }
    if (blockIdx.x < (unsigned)(gE + 97)) {
        int i = (blockIdx.x - gE) * 256 + threadIdx.x;
        const float g = sigmoid_f(gatep[0]);
        if (i < 16384) {
            int n = i >> 7, k = i & 127;
            float a  = Wl[k * 128 + n];
            float w0 = W0[k * 128 + n];
            float w1 = W1[k * 128 + n];
            float c  = (1.f - g) * w0 + g * w1;
            int off = ((k >> 5) * 128 + n) * 32 + (k & 31);
            split_store(a, wlh + off, wll + off);
            split_store(c, wch + off, wcl + off);
        } else if (i < 24576) {
            int j = i - 16384;
            int n = j >> 7, k = j & 127;
            float v = Wout[k * 64 + n];
            int off = ((k >> 5) * 64 + n) * 32 + (k & 31);
            split_store(v, woh + off, wol + off);
        } else if (i < 24704) {
            int t = i - 24576;
            bc[t] = bl[t] + (1.f - g) * b0[t] + g * b1[t];
        }
        return;
    }
    long long e8 = ((long long)(blockIdx.x - gE - 97) * 256 + threadIdx.x) * 8;
    if (e8 < (long long)N * HD) {
        float4 u0 = *reinterpret_cast<const float4*>(xC + e8);
        float4 u1 = *reinterpret_cast<const float4*>(xC + e8 + 4);
        float f[8] = {u0.x, u0.y, u0.z, u0.w, u1.x, u1.y, u1.z, u1.w};
        Frag hi, lo;
        split_pack8(f, &hi, &lo);
        *reinterpret_cast<uint4*>(xch + e8) = hi.q;
        *reinterpret_cast<uint4*>(xcl + e8) = lo.q;
    }
}

// ---------------------------------------------------------------- scan
__global__ __launch_bounds__(256) void k_scan1(
    const int* __restrict__ cnt, int* __restrict__ offs,
    int* __restrict__ part, int* __restrict__ tot, int N)
{
    __shared__ int sh[256];
    const int t = threadIdx.x;
    const int base = blockIdx.x * SCAN_E + t * 4;
    int v[4], sum = 0;
#pragma unroll
    for (int i = 0; i < 4; ++i) {
        int idx = base + i;
        v[i] = (idx < N) ? cnt[idx] : 0;
        sum += v[i];
    }
    sh[t] = sum;
    __syncthreads();
    for (int off = 1; off < 256; off <<= 1) {
        int x = (t >= off) ? sh[t - off] : 0;
        __syncthreads();
        sh[t] += x;
        __syncthreads();
    }
    int run = (t > 0) ? sh[t - 1] : 0;
    if (t == 255) part[blockIdx.x] = atomicAdd(tot, sh[255]);
#pragma unroll
    for (int i = 0; i < 4; ++i) {
        int idx = base + i;
        if (idx < N) offs[idx] = run;
        run += v[i];
    }
}

// ---------------------------------------------------------------- CSR fill + weight + wmax
__global__ __launch_bounds__(256) void k_fillw(
    const int* __restrict__ edge, const float* __restrict__ tB,
    const float* __restrict__ tC, const float* __restrict__ lam_raw,
    const int* __restrict__ offs, const int* __restrict__ part,
    int* __restrict__ fillc, int* __restrict__ wmax,
    int2* __restrict__ srcw, int E)
{
    int e = blockIdx.x * 256 + threadIdx.x;
    if (e >= E) return;
    int s = edge[e];
    int d = edge[E + e];
    float lam = softplus_f(lam_raw[0]) + 1e-8f;
    float dt  = fmaxf(tC[d] - tB[s], 0.0f);
    float w   = expf(fmaxf(-lam * dt, -60.0f));
    int pos = offs[d] + part[d >> 10] + atomicAdd(fillc + d, 1);
    srcw[pos] = make_int2(s, __float_as_int(w));
    atomicMax(wmax + d, __float_as_int(w));   // w>0: int order == float order
}

// ---------------------------------------------------------------- gather
// wave per node; 4 edge slots x 16 lanes; skip rows with w < wmax*1e-8
__global__ __launch_bounds__(256) void k_gather(
    const float* __restrict__ xB, const int2* __restrict__ srcw,
    const int* __restrict__ offs, const int* __restrict__ part,
    const int* __restrict__ cnt, const int* __restrict__ wmax,
    u16* __restrict__ aggh, u16* __restrict__ aggl, int N)
{
    const int wave = (blockIdx.x * 256 + threadIdx.x) >> 6;
    const int lane = threadIdx.x & 63;
    const int slot = lane >> 4;
    const int l4   = lane & 15;
    if (wave >= N) return;
    const int r    = wave;
    const int degc = cnt[r];

    if (degc == 0) {
        if (slot == 0) {
            uint4 z = make_uint4(0, 0, 0, 0);
            *reinterpret_cast<uint4*>(aggh + (size_t)r * HD + l4 * 8) = z;
            *reinterpret_cast<uint4*>(aggl + (size_t)r * HD + l4 * 8) = z;
        }
        return;
    }

    const int start = offs[r] + part[r >> 10];
    const float thr = __int_as_float(wmax[r]) * 1e-8f;
    float4 a0 = make_float4(0, 0, 0, 0), a1 = make_float4(0, 0, 0, 0);
    float sw = 0.f;
#pragma unroll 2
    for (int j = slot; j < degc; j += 4) {
        int2 swp = srcw[start + j];
        float w = __int_as_float(swp.y);
        if (w < thr) continue;               // negligible (<1e-8 relative)
        const float* row = xB + (size_t)swp.x * HD + l4 * 8;
        float4 x0 = *reinterpret_cast<const float4*>(row);
        float4 x1 = *reinterpret_cast<const float4*>(row + 4);
        a0.x = fmaf(w, x0.x, a0.x); a0.y = fmaf(w, x0.y, a0.y);
        a0.z = fmaf(w, x0.z, a0.z); a0.w = fmaf(w, x0.w, a0.w);
        a1.x = fmaf(w, x1.x, a1.x); a1.y = fmaf(w, x1.y, a1.y);
        a1.z = fmaf(w, x1.z, a1.z); a1.w = fmaf(w, x1.w, a1.w);
        sw += w;
    }
#pragma unroll
    for (int m = 16; m <= 32; m <<= 1) {
        a0.x += __shfl_xor(a0.x, m); a0.y += __shfl_xor(a0.y, m);
        a0.z += __shfl_xor(a0.z, m); a0.w += __shfl_xor(a0.w, m);
        a1.x += __shfl_xor(a1.x, m); a1.y += __shfl_xor(a1.y, m);
        a1.z += __shfl_xor(a1.z, m); a1.w += __shfl_xor(a1.w, m);
        sw   += __shfl_xor(sw, m);
    }
    float inv = 1.0f / fmaxf(sw, 1e-6f);
    if (slot == 0) {
        float f[8] = {a0.x * inv, a0.y * inv, a0.z * inv, a0.w * inv,
                      a1.x * inv, a1.y * inv, a1.z * inv, a1.w * inv};
        Frag hi, lo;
        split_pack8(f, &hi, &lo);
        *reinterpret_cast<uint4*>(aggh + (size_t)r * HD + l4 * 8) = hi.q;
        *reinterpret_cast<uint4*>(aggl + (size_t)r * HD + l4 * 8) = lo.q;
    }
}

// ---------------------------------------------------------------- fused K2+K3
// block = 256 thr = 4 waves; wave owns 32 rows x 128 cols.
// LDS 64KB: [0,32K) A per-wave dbuf (-> hc slices in epilogue);
//           [32K,64K) B block dbuf (-> K3 woh|wol after K2).
__global__ __launch_bounds__(256) void k_fused(
    const u16* __restrict__ aggh, const u16* __restrict__ aggl,
    const u16* __restrict__ xch, const u16* __restrict__ xcl,
    const float* __restrict__ xC, const int* __restrict__ cnt,
    const u16* __restrict__ wlh, const u16* __restrict__ wll,
    const u16* __restrict__ wch, const u16* __restrict__ wcl,
    const u16* __restrict__ woh, const u16* __restrict__ wol,
    const float* __restrict__ bc, const float* __restrict__ lng,
    const float* __restrict__ lnb, const float* __restrict__ bout,
    float* __restrict__ out, int N)
{
    __shared__ char lds[65536];

    const int lane = threadIdx.x & 63;
    const int wid  = threadIdx.x >> 6;
    const int lr   = lane & 15;
    const int kb   = lane >> 4;
    const int row0 = blockIdx.x * 128 + wid * 32;
    char* myA = lds + wid * 8192;
    char* abufs[2] = {myA, myA + 4096};
    char* bbufs[2] = {lds + 32768, lds + 32768 + 16384};

    const u16* Ahp[2] = {aggh, xch};
    const u16* Alp[2] = {aggl, xcl};
    const u16* Bhp[2] = {wlh, wch};
    const u16* Blp[2] = {wll, wcl};

    v4f acc[2][8] = {};

    // ---- prologue: 2 chunks in flight (8 loads each: 4 A + 4 B)
    stage_A(Ahp[0], Alp[0], 0, abufs[0], row0, lane, N);
    stage_B(Bhp[0], Blp[0], 0, bbufs[0], wid, lane);
    stage_A(Ahp[0], Alp[0], 1, abufs[1], row0, lane, N);
    stage_B(Bhp[0], Blp[0], 1, bbufs[1], wid, lane);

#pragma unroll
    for (int ch = 0; ch < 8; ++ch) {
        const int mat = ch >> 2;
        if (ch == 7) {
            asm volatile("s_waitcnt vmcnt(0)" ::: "memory");
        } else {
            asm volatile("s_waitcnt vmcnt(8)" ::: "memory");
        }
        __builtin_amdgcn_s_barrier();       // B chunk ch visible to all waves

        const char* ca = abufs[ch & 1];
        const char* cb = bbufs[ch & 1];

        Frag ah[2], al[2];
#pragma unroll
        for (int rt = 0; rt < 2; ++rt) {
            ah[rt].q = *reinterpret_cast<const uint4*>(ca + rt * 1024 + lane * 16);
            al[rt].q = *reinterpret_cast<const uint4*>(ca + 2048 + rt * 1024 + lane * 16);
        }
        Frag bh[8], bl[8];
#pragma unroll
        for (int ct = 0; ct < 8; ++ct) {
            int bo = (((ct * 16 + lr) * 4 + kb) << 4);
            bh[ct].q = *reinterpret_cast<const uint4*>(cb + bo);
            bl[ct].q = *reinterpret_cast<const uint4*>(cb + 8192 + bo);
        }
        asm volatile("s_waitcnt lgkmcnt(0)" ::: "memory");
        __builtin_amdgcn_sched_barrier(0);
        __builtin_amdgcn_s_barrier();       // all waves done reading buf[ch&1]

        if (ch + 2 < 8) {
            const int nc = ch + 2;
            stage_A(Ahp[nc >> 2], Alp[nc >> 2], nc & 3, abufs[ch & 1], row0, lane, N);
            stage_B(Bhp[nc >> 2], Blp[nc >> 2], nc & 3, bbufs[ch & 1], wid, lane);
        }

#pragma unroll
        for (int ct = 0; ct < 8; ++ct) {
#pragma unroll
            for (int rt = 0; rt < 2; ++rt) {
                acc[rt][ct] = __builtin_amdgcn_mfma_f32_16x16x32_bf16(
                    ah[rt].v, bh[ct].v, acc[rt][ct], 0, 0, 0);
                acc[rt][ct] = __builtin_amdgcn_mfma_f32_16x16x32_bf16(
                    ah[rt].v, bl[ct].v, acc[rt][ct], 0, 0, 0);
                acc[rt][ct] = __builtin_amdgcn_mfma_f32_16x16x32_bf16(
                    al[rt].v, bh[ct].v, acc[rt][ct], 0, 0, 0);
            }
        }
        (void)mat;
    }

    // ---- stage K3 weights (woh|wol contiguous 32KB) into B region
    __builtin_amdgcn_s_barrier();           // K2 B reads all done (lgkm drained)
#pragma unroll
    for (int i = 0; i < 8; ++i) {
        int seg = wid * 8 + i;
        gload_lds16((const char*)woh + seg * 1024 + lane * 16,
                    lds + 32768 + seg * 1024);
    }

    // ---- per-column constants
    float bcv[8], gav[8], bev[8];
#pragma unroll
    for (int ct = 0; ct < 8; ++ct) {
        int c = ct * 16 + lr;
        bcv[ct] = bc[c];
        gav[ct] = lng[c];
        bev[ct] = lnb[c];
    }
    float bov[4];
#pragma unroll
    for (int ct = 0; ct < 4; ++ct) bov[ct] = bout[ct * 16 + lr];

    float* hc = (float*)myA;               // 16x128 fp32 slice (8KB, recycled)
    bool b3ready = false;

    // ======== per 16-row tile: epilogue -> slice -> K3 -> out ========
#pragma unroll
    for (int rt = 0; rt < 2; ++rt) {
        int rq = row0 + rt * 16 + kb * 4;
        int cvr[4] = {0, 0, 0, 0};
        if (rq < N) {                        // N%4==0, rq%4==0 -> rq+3 < N
            int4 cv = *(const int4*)(cnt + rq);
            cvr[0] = cv.x; cvr[1] = cv.y; cvr[2] = cv.z; cvr[3] = cv.w;
        }
#pragma unroll
        for (int reg = 0; reg < 4; ++reg) {
            int rloc = kb * 4 + reg;
            int r    = rq + reg;
            float yv[8];
            float s = 0.f, q = 0.f;
#pragma unroll
            for (int ct = 0; ct < 8; ++ct) {
                float v = acc[rt][ct][reg] + bcv[ct];
                v = fmaxf(v, 0.0f);
                yv[ct] = v;
                s += v;
                q += v * v;
            }
#pragma unroll
            for (int m = 1; m < 16; m <<= 1) {
                s += __shfl_xor(s, m);
                q += __shfl_xor(q, m);
            }
            float mu   = s * (1.0f / 128.0f);
            float var  = q * (1.0f / 128.0f) - mu * mu;
            float rstd = rsqrtf(var + 1e-5f);

            if (r < N) {
                if (cvr[reg] > 0) {
#pragma unroll
                    for (int ct = 0; ct < 8; ++ct)
                        hc[swz(rloc, ct * 16 + lr)] =
                            (yv[ct] - mu) * rstd * gav[ct] + bev[ct];
                } else {
                    size_t base = (size_t)r * HD;
#pragma unroll
                    for (int ct = 0; ct < 8; ++ct)
                        hc[swz(rloc, ct * 16 + lr)] = xC[base + ct * 16 + lr];
                }
            } else {
#pragma unroll
                for (int ct = 0; ct < 8; ++ct)
                    hc[swz(rloc, ct * 16 + lr)] = 0.0f;
            }
        }

        if (!b3ready) {                      // B3 staged before first K3 use
            asm volatile("s_waitcnt vmcnt(0)" ::: "memory");
            __builtin_amdgcn_s_barrier();
            b3ready = true;
        }

        // ---- K3 on this 16-row tile (B3 from LDS)
        v4f acc2[4] = {};
#pragma unroll
        for (int kc = 0; kc < 4; ++kc) {
            Frag ah, al;
            {
                int c0 = kc * 32 + kb * 8;
                float4 u0 = *reinterpret_cast<const float4*>(&hc[swz(lr, c0)]);
                float4 u1 = *reinterpret_cast<const float4*>(&hc[swz(lr, c0 + 4)]);
                float f[8] = {u0.x, u0.y, u0.z, u0.w, u1.x, u1.y, u1.z, u1.w};
                cvt_split8(f, ah.u, al.u);
            }
#pragma unroll
            for (int ct = 0; ct < 4; ++ct) {
                int bo = ((kc * 256 + (ct * 16 + lr) * 4 + kb) << 4);
                Frag b3h, b3l;
                b3h.q = *reinterpret_cast<const uint4*>(lds + 32768 + bo);
                b3l.q = *reinterpret_cast<const uint4*>(lds + 49152 + bo);
                acc2[ct] = __builtin_amdgcn_mfma_f32_16x16x32_bf16(
                    ah.v, b3h.v, acc2[ct], 0, 0, 0);
                acc2[ct] = __builtin_amdgcn_mfma_f32_16x16x32_bf16(
                    ah.v, b3l.v, acc2[ct], 0, 0, 0);
                acc2[ct] = __builtin_amdgcn_mfma_f32_16x16x32_bf16(
                    al.v, b3h.v, acc2[ct], 0, 0, 0);
            }
        }

#pragma unroll
        for (int reg = 0; reg < 4; ++reg) {
            int r = rq + reg;
            if (r < N) {
#pragma unroll
                for (int ct = 0; ct < 4; ++ct)
                    out[(size_t)r * OD + ct * 16 + lr] = acc2[ct][reg] + bov[ct];
            }
        }
    }
}

// ---------------------------------------------------------------- launch
extern "C" void kernel_launch(void* const* d_in, const int* in_sizes, int n_in,
                              void* d_out, int out_size, void* d_ws, size_t ws_size,
                              hipStream_t stream) {
    const float* xB    = (const float*)d_in[1];
    const float* xC    = (const float*)d_in[2];
    const float* tB    = (const float*)d_in[4];
    const float* tC    = (const float*)d_in[5];
    const int*   edge2 = (const int*)d_in[7];
    const float* Wl1   = (const float*)d_in[18];
    const float* bl1   = (const float*)d_in[19];
    const float* W01   = (const float*)d_in[20];
    const float* b01   = (const float*)d_in[21];
    const float* W11   = (const float*)d_in[22];
    const float* b11   = (const float*)d_in[23];
    const float* gate1 = (const float*)d_in[24];
    const float* lam1  = (const float*)d_in[25];
    const float* lng1  = (const float*)d_in[26];
    const float* lnb1  = (const float*)d_in[27];
    const float* Wout  = (const float*)d_in[28];
    const float* bout  = (const float*)d_in[29];

    const int N = in_sizes[2] / HD;
    const int E = in_sizes[7] / 2;

    int*   cnt   = (int*)d_ws;
    int*   fillc = cnt + N;
    int*   wmax  = fillc + N;
    int*   offs  = wmax + N;
    int*   part  = offs + N;
    int*   tot   = part + 128;
    int2*  srcw  = (int2*)(tot + 4);
    u16*   wlh   = (u16*)(srcw + E);
    u16*   wll   = wlh + 16384;
    u16*   wch   = wll + 16384;
    u16*   wcl   = wch + 16384;
    u16*   woh   = wcl + 16384;
    u16*   wol   = woh + 8192;
    float* bc    = (float*)(wol + 8192);
    u16*   aggh  = (u16*)(bc + 128);
    u16*   aggl  = aggh + (size_t)N * HD;
    u16*   xch   = aggl + (size_t)N * HD;
    u16*   xcl   = xch + (size_t)N * HD;

    hipMemsetAsync(cnt, 0, (size_t)3 * N * sizeof(int), stream);
    hipMemsetAsync(tot, 0, sizeof(int), stream);

    dim3 blk(256);
    const int gE = (E + 255) / 256;
    const int NB = (N + SCAN_E - 1) / SCAN_E;
    const int gX = (N * (HD / 8) + 255) / 256;

    k_prep <<<gE + 97 + gX, blk, 0, stream>>>(edge2, cnt, E, gE,
                                              Wl1, W01, W11, Wout, bl1, b01, b11,
                                              gate1, xC, wlh, wll, wch, wcl,
                                              woh, wol, bc, xch, xcl, N);
    k_scan1<<<NB, blk, 0, stream>>>(cnt, offs, part, tot, N);
    k_fillw<<<gE, blk, 0, stream>>>(edge2, tB, tC, lam1, offs, part, fillc,
                                    wmax, srcw, E);

    const int gN64 = (N * 64 + 255) / 256;
    k_gather<<<gN64, blk, 0, stream>>>(xB, srcw, offs, part, cnt, wmax,
                                       aggh, aggl, N);

    const int GB = (N + 127) / 128;
    k_fused<<<GB, blk, 0, stream>>>(aggh, aggl, xch, xcl, xC, cnt,
                                    wlh, wll, wch, wcl, woh, wol,
                                    bc, lng1, lnb1, bout, (float*)d_out, N);
}

// Round 21
// 214.002 us; speedup vs baseline: 1.3094x; 1.1123x over previous
//
#include <hip/hip_runtime.h>

// MetaPathGNN — only the edge2 (B->C) layer + output GEMM matter.
//
// R19 (third submit; source unchanged — two consecutive UnresponsiveContainer
// infra failures, never executed): rollback to the measured-best combination
// + coalesced B-frag planes.
//  - R10 fused core: A read fp32 from global + in-reg bf16 split (the bf16
//    A-plane detour of R15-R18 cost +20us prep for 0 fused gain — reverted).
//  - R10 gather (no edge-skip: R18 showed skip = -74MB FETCH but +10us,
//    gather is latency- not BW-bound).
//  - NEW: B planes stored in FRAG ORDER (uint4 slot (kc*8+ct)*64+lane) so
//    each B-frag load is one coalesced 1KB transaction instead of 64x16B
//    at 64B stride (the suspected request-issue serializer behind the
//    9-variant 80us plateau: all pipes idle, Mfma~11%).
//  - merged prep (hist|wprep one grid), single-pass scan (atomic base).
//
// ws (ints): [cnt N | fillc N | offs N | part 128 | tot 4 | srcw 2E |
//             wlh/wll/wch/wcl 16384u16 | woh/wol 8192u16 | bc 128f | buf N*128f]

#define HD 128
#define OD 64
#define SCAN_E 1024

typedef unsigned short u16;
typedef short v8s __attribute__((ext_vector_type(8)));
typedef float v4f __attribute__((ext_vector_type(4)));

union Frag {
    unsigned int u[4];
    uint4 q;
    v8s v;
};

__device__ __forceinline__ float softplus_f(float x) {
    return fmaxf(x, 0.0f) + log1pf(expf(-fabsf(x)));
}
__device__ __forceinline__ float sigmoid_f(float x) {
    return 1.0f / (1.0f + expf(-x));
}
// swizzled LDS offset within a [32][128] fp32 slice: granule XOR row&7
__device__ __forceinline__ int swz(int r, int c) {
    int g = (c >> 2) ^ (r & 7);
    return r * 128 + g * 4 + (c & 3);
}

// split x into bf16 hi + bf16 lo (truncation split; residual ~2^-17 |x|)
__device__ __forceinline__ void split_store(float x, u16* ph, u16* pl) {
    unsigned int b = __float_as_uint(x);
    unsigned int h = b & 0xffff0000u;
    *ph = (u16)(h >> 16);
    float r = x - __uint_as_float(h);
    *pl = (u16)(__float_as_uint(r) >> 16);
}

// 8 floats -> 4 packed dwords hi, 4 packed dwords lo (2 bf16 per dword)
__device__ __forceinline__ void cvt_split8(const float* f, unsigned int* hi,
                                           unsigned int* lo) {
#pragma unroll
    for (int j = 0; j < 4; ++j) {
        unsigned int b0 = __float_as_uint(f[2 * j]);
        unsigned int b1 = __float_as_uint(f[2 * j + 1]);
        unsigned int h0 = b0 & 0xffff0000u;
        unsigned int h1 = b1 & 0xffff0000u;
        hi[j] = (h0 >> 16) | h1;
        float r0 = f[2 * j]     - __uint_as_float(h0);
        float r1 = f[2 * j + 1] - __uint_as_float(h1);
        lo[j] = (__float_as_uint(r0) >> 16) | (__float_as_uint(r1) & 0xffff0000u);
    }
}

// ---------------------------------------------------------------- prep: hist | wprep
// B planes in FRAG ORDER: element (k,n) -> u16 offset
//   K2 (128 cols): (((k>>5)*8 + (n>>4))*64 + ((k&31)>>3)*16 + (n&15))*8 + (k&7)
//   K3 ( 64 cols): (((k>>5)*4 + (n>>4))*64 + ((k&31)>>3)*16 + (n&15))*8 + (k&7)
__global__ __launch_bounds__(256) void k_prep(
    const int* __restrict__ edge, int* __restrict__ cnt, int E, int gE,
    const float* __restrict__ Wl, const float* __restrict__ W0,
    const float* __restrict__ W1, const float* __restrict__ Wout,
    const float* __restrict__ bl, const float* __restrict__ b0,
    const float* __restrict__ b1, const float* __restrict__ gatep,
    u16* __restrict__ wlh, u16* __restrict__ wll,
    u16* __restrict__ wch, u16* __restrict__ wcl,
    u16* __restrict__ woh, u16* __restrict__ wol, float* __restrict__ bc)
{
    if (blockIdx.x < (unsigned)gE) {
        int e = blockIdx.x * 256 + threadIdx.x;
        if (e < E) atomicAdd(cnt + edge[E + e], 1);
        return;
    }
    int i = (blockIdx.x - gE) * 256 + threadIdx.x;
    const float g = sigmoid_f(gatep[0]);
    if (i < 16384) {
        int n = i >> 7, k = i & 127;
        float a  = Wl[k * 128 + n];
        float w0 = W0[k * 128 + n];
        float w1 = W1[k * 128 + n];
        float c  = (1.f - g) * w0 + g * w1;
        int off = (((k >> 5) * 8 + (n >> 4)) * 64 +
                   ((k & 31) >> 3) * 16 + (n & 15)) * 8 + (k & 7);
        split_store(a, wlh + off, wll + off);
        split_store(c, wch + off, wcl + off);
    } else if (i < 24576) {
        int j = i - 16384;
        int n = j >> 7, k = j & 127;          // n 0..63, k 0..127
        float v = Wout[k * 64 + n];
        int off = (((k >> 5) * 4 + (n >> 4)) * 64 +
                   ((k & 31) >> 3) * 16 + (n & 15)) * 8 + (k & 7);
        split_store(v, woh + off, wol + off);
    } else if (i < 24704) {
        int t = i - 24576;
        bc[t] = bl[t] + (1.f - g) * b0[t] + g * b1[t];
    }
}

// ---------------------------------------------------------------- scan (1-pass, atomic base)
__global__ __launch_bounds__(256) void k_scan1(
    const int* __restrict__ cnt, int* __restrict__ offs,
    int* __restrict__ part, int* __restrict__ tot, int N)
{
    __shared__ int sh[256];
    const int t = threadIdx.x;
    const int base = blockIdx.x * SCAN_E + t * 4;
    int v[4], sum = 0;
#pragma unroll
    for (int i = 0; i < 4; ++i) {
        int idx = base + i;
        v[i] = (idx < N) ? cnt[idx] : 0;
        sum += v[i];
    }
    sh[t] = sum;
    __syncthreads();
    for (int off = 1; off < 256; off <<= 1) {
        int x = (t >= off) ? sh[t - off] : 0;
        __syncthreads();
        sh[t] += x;
        __syncthreads();
    }
    int run = (t > 0) ? sh[t - 1] : 0;
    if (t == 255) part[blockIdx.x] = atomicAdd(tot, sh[255]);
#pragma unroll
    for (int i = 0; i < 4; ++i) {
        int idx = base + i;
        if (idx < N) offs[idx] = run;
        run += v[i];
    }
}

// ---------------------------------------------------------------- CSR fill + weight
__global__ __launch_bounds__(256) void k_fillw(
    const int* __restrict__ edge, const float* __restrict__ tB,
    const float* __restrict__ tC, const float* __restrict__ lam_raw,
    const int* __restrict__ offs, const int* __restrict__ part,
    int* __restrict__ fillc, int2* __restrict__ srcw, int E)
{
    int e = blockIdx.x * 256 + threadIdx.x;
    if (e >= E) return;
    int s = edge[e];
    int d = edge[E + e];
    float lam = softplus_f(lam_raw[0]) + 1e-8f;
    float dt  = fmaxf(tC[d] - tB[s], 0.0f);
    float w   = expf(fmaxf(-lam * dt, -60.0f));
    int pos = offs[d] + part[d >> 10] + atomicAdd(fillc + d, 1);
    srcw[pos] = make_int2(s, __float_as_int(w));
}

// ---------------------------------------------------------------- gather
// wave per node; 4 edge slots x 16 lanes; lane covers cols [l4*4) and [64+l4*4)
__global__ __launch_bounds__(256) void k_gather(
    const float* __restrict__ xB, const int2* __restrict__ srcw,
    const int* __restrict__ offs, const int* __restrict__ part,
    const int* __restrict__ cnt, float* __restrict__ aggn, int N)
{
    const int wave = (blockIdx.x * 256 + threadIdx.x) >> 6;
    const int lane = threadIdx.x & 63;
    const int slot = lane >> 4;
    const int l4   = lane & 15;
    if (wave >= N) return;
    const int r    = wave;
    const int degc = cnt[r];

    float* dstp = aggn + (size_t)r * HD;
    if (degc == 0) {
        if (slot == 0) {
            *reinterpret_cast<float4*>(dstp + l4 * 4) = make_float4(0, 0, 0, 0);
            *reinterpret_cast<float4*>(dstp + 64 + l4 * 4) = make_float4(0, 0, 0, 0);
        }
        return;
    }

    const int start = offs[r] + part[r >> 10];
    float4 a0 = make_float4(0, 0, 0, 0), a1 = make_float4(0, 0, 0, 0);
    float sw = 0.f;
#pragma unroll 2
    for (int j = slot; j < degc; j += 4) {
        int2 swp = srcw[start + j];
        float w = __int_as_float(swp.y);
        const float* row = xB + (size_t)swp.x * HD;
        float4 x0 = *reinterpret_cast<const float4*>(row + l4 * 4);
        float4 x1 = *reinterpret_cast<const float4*>(row + 64 + l4 * 4);
        a0.x = fmaf(w, x0.x, a0.x); a0.y = fmaf(w, x0.y, a0.y);
        a0.z = fmaf(w, x0.z, a0.z); a0.w = fmaf(w, x0.w, a0.w);
        a1.x = fmaf(w, x1.x, a1.x); a1.y = fmaf(w, x1.y, a1.y);
        a1.z = fmaf(w, x1.z, a1.z); a1.w = fmaf(w, x1.w, a1.w);
        sw += w;
    }
#pragma unroll
    for (int m = 16; m <= 32; m <<= 1) {
        a0.x += __shfl_xor(a0.x, m); a0.y += __shfl_xor(a0.y, m);
        a0.z += __shfl_xor(a0.z, m); a0.w += __shfl_xor(a0.w, m);
        a1.x += __shfl_xor(a1.x, m); a1.y += __shfl_xor(a1.y, m);
        a1.z += __shfl_xor(a1.z, m); a1.w += __shfl_xor(a1.w, m);
        sw   += __shfl_xor(sw, m);
    }
    float inv = 1.0f / fmaxf(sw, 1e-6f);
    if (slot == 0) {
        a0.x *= inv; a0.y *= inv; a0.z *= inv; a0.w *= inv;
        a1.x *= inv; a1.y *= inv; a1.z *= inv; a1.w *= inv;
        *reinterpret_cast<float4*>(dstp + l4 * 4) = a0;
        *reinterpret_cast<float4*>(dstp + 64 + l4 * 4) = a1;
    }
}

// ---------------------------------------------------------------- fused K2+K3
// block = 256 thr = 4 waves; wave owns 32 rows.  K2: acc[2][8] over K=256
// (agg@Wl then xC@Wc), A fp32 global->reg + in-reg split; B frag-order
// coalesced 1KB loads.  Epilogue -> per-wave 16KB LDS slice -> K3 -> out.
__global__ __launch_bounds__(256) void k_fused(
    const float* __restrict__ xC, const float* __restrict__ aggn,
    const int* __restrict__ cnt,
    const u16* __restrict__ wlh, const u16* __restrict__ wll,
    const u16* __restrict__ wch, const u16* __restrict__ wcl,
    const u16* __restrict__ woh, const u16* __restrict__ wol,
    const float* __restrict__ bc, const float* __restrict__ lng,
    const float* __restrict__ lnb, const float* __restrict__ bout,
    float* __restrict__ out, int N)
{
    __shared__ float lds[4 * 32 * 128];     // 64 KB, per-wave 16KB slices

    const int lane = threadIdx.x & 63;
    const int wid  = threadIdx.x >> 6;
    const int lr   = lane & 15;        // frag row (A) / col (B/C)
    const int kb   = lane >> 4;        // k-block 0..3
    const int row0 = blockIdx.x * 128 + wid * 32;
    float* myl = lds + wid * 32 * 128;

    // ================= K2 =================
    v4f acc[2][8] = {};

#pragma unroll
    for (int mat = 0; mat < 2; ++mat) {
        const float* Asrc = mat ? xC : aggn;
        const uint4* BH = (const uint4*)(mat ? wch : wlh);
        const uint4* BL = (const uint4*)(mat ? wcl : wll);
#pragma unroll
        for (int kc = 0; kc < 4; ++kc) {
            Frag ah[2], al[2];
#pragma unroll
            for (int rt = 0; rt < 2; ++rt) {
                int r = row0 + rt * 16 + lr;
                r = (r < N) ? r : (N - 1);
                const float4* ap = (const float4*)(
                    Asrc + (size_t)r * HD + kc * 32 + kb * 8);
                float4 u0 = ap[0], u1 = ap[1];
                float f[8] = {u0.x, u0.y, u0.z, u0.w, u1.x, u1.y, u1.z, u1.w};
                cvt_split8(f, ah[rt].u, al[rt].u);
            }
#pragma unroll
            for (int ct = 0; ct < 8; ++ct) {
                int idx = (kc * 8 + ct) * 64 + lane;   // coalesced 1KB
                Frag bh, bl;
                bh.q = BH[idx];
                bl.q = BL[idx];
#pragma unroll
                for (int rt = 0; rt < 2; ++rt) {
                    acc[rt][ct] = __builtin_amdgcn_mfma_f32_16x16x32_bf16(
                        ah[rt].v, bh.v, acc[rt][ct], 0, 0, 0);
                    acc[rt][ct] = __builtin_amdgcn_mfma_f32_16x16x32_bf16(
                        ah[rt].v, bl.v, acc[rt][ct], 0, 0, 0);
                    acc[rt][ct] = __builtin_amdgcn_mfma_f32_16x16x32_bf16(
                        al[rt].v, bh.v, acc[rt][ct], 0, 0, 0);
                }
            }
        }
    }

    // ---- epilogue: bias, relu, LN (shfl over 16-lane group), select -> LDS
    float bcv[8], gav[8], bev[8];
#pragma unroll
    for (int ct = 0; ct < 8; ++ct) {
        int c = ct * 16 + lr;
        bcv[ct] = bc[c];
        gav[ct] = lng[c];
        bev[ct] = lnb[c];
    }

#pragma unroll
    for (int rt = 0; rt < 2; ++rt) {
        int rq = row0 + rt * 16 + kb * 4;    // first of this lane's 4 rows
        int cvr[4] = {0, 0, 0, 0};
        if (rq < N) {                        // N%4==0, rq%4==0 -> rq+3 < N
            int4 cv = *(const int4*)(cnt + rq);
            cvr[0] = cv.x; cvr[1] = cv.y; cvr[2] = cv.z; cvr[3] = cv.w;
        }
#pragma unroll
        for (int reg = 0; reg < 4; ++reg) {
            int rloc = rt * 16 + kb * 4 + reg;
            int r    = rq + reg;
            float yv[8];
            float s = 0.f, q = 0.f;
#pragma unroll
            for (int ct = 0; ct < 8; ++ct) {
                float v = acc[rt][ct][reg] + bcv[ct];
                v = fmaxf(v, 0.0f);
                yv[ct] = v;
                s += v;
                q += v * v;
            }
#pragma unroll
            for (int m = 1; m < 16; m <<= 1) {
                s += __shfl_xor(s, m);
                q += __shfl_xor(q, m);
            }
            float mu   = s * (1.0f / 128.0f);
            float var  = q * (1.0f / 128.0f) - mu * mu;
            float rstd = rsqrtf(var + 1e-5f);

            if (r < N) {
                if (cvr[reg] > 0) {
#pragma unroll
                    for (int ct = 0; ct < 8; ++ct)
                        myl[swz(rloc, ct * 16 + lr)] =
                            (yv[ct] - mu) * rstd * gav[ct] + bev[ct];
                } else {
                    size_t base = (size_t)r * HD;
#pragma unroll
                    for (int ct = 0; ct < 8; ++ct)
                        myl[swz(rloc, ct * 16 + lr)] = xC[base + ct * 16 + lr];
                }
            } else {
#pragma unroll
                for (int ct = 0; ct < 8; ++ct)
                    myl[swz(rloc, ct * 16 + lr)] = 0.0f;
            }
        }
    }

    __syncthreads();   // order LDS writes before K3 reads (wave-local, but safe)

    // ================= K3 =================
    v4f acc2[2][4] = {};
    const uint4* BH3 = (const uint4*)woh;
    const uint4* BL3 = (const uint4*)wol;

#pragma unroll
    for (int kc = 0; kc < 4; ++kc) {
        Frag ah[2], al[2];
#pragma unroll
        for (int rt = 0; rt < 2; ++rt) {
            int rloc = rt * 16 + lr;
            int c0   = kc * 32 + kb * 8;
            float4 u0 = *reinterpret_cast<const float4*>(&myl[swz(rloc, c0)]);
            float4 u1 = *reinterpret_cast<const float4*>(&myl[swz(rloc, c0 + 4)]);
            float f[8] = {u0.x, u0.y, u0.z, u0.w, u1.x, u1.y, u1.z, u1.w};
            cvt_split8(f, ah[rt].u, al[rt].u);
        }
#pragma unroll
        for (int ct = 0; ct < 4; ++ct) {
            int idx = (kc * 4 + ct) * 64 + lane;   // coalesced 1KB
            Frag bh, bl;
            bh.q = BH3[idx];
            bl.q = BL3[idx];
#pragma unroll
            for (int rt = 0; rt < 2; ++rt) {
                acc2[rt][ct] = __builtin_amdgcn_mfma_f32_16x16x32_bf16(
                    ah[rt].v, bh.v, acc2[rt][ct], 0, 0, 0);
                acc2[rt][ct] = __builtin_amdgcn_mfma_f32_16x16x32_bf16(
                    ah[rt].v, bl.v, acc2[rt][ct], 0, 0, 0);
                acc2[rt][ct] = __builtin_amdgcn_mfma_f32_16x16x32_bf16(
                    al[rt].v, bh.v, acc2[rt][ct], 0, 0, 0);
            }
        }
    }

    float bov[4];
#pragma unroll
    for (int ct = 0; ct < 4; ++ct) bov[ct] = bout[ct * 16 + lr];

#pragma unroll
    for (int rt = 0; rt < 2; ++rt) {
#pragma unroll
        for (int reg = 0; reg < 4; ++reg) {
            int r = row0 + rt * 16 + kb * 4 + reg;
            if (r < N) {
#pragma unroll
                for (int ct = 0; ct < 4; ++ct)
                    out[(size_t)r * OD + ct * 16 + lr] =
                        acc2[rt][ct][reg] + bov[ct];
            }
        }
    }
}

// ---------------------------------------------------------------- launch
extern "C" void kernel_launch(void* const* d_in, const int* in_sizes, int n_in,
                              void* d_out, int out_size, void* d_ws, size_t ws_size,
                              hipStream_t stream) {
    const float* xB    = (const float*)d_in[1];
    const float* xC    = (const float*)d_in[2];
    const float* tB    = (const float*)d_in[4];
    const float* tC    = (const float*)d_in[5];
    const int*   edge2 = (const int*)d_in[7];
    const float* Wl1   = (const float*)d_in[18];
    const float* bl1   = (const float*)d_in[19];
    const float* W01   = (const float*)d_in[20];
    const float* b01   = (const float*)d_in[21];
    const float* W11   = (const float*)d_in[22];
    const float* b11   = (const float*)d_in[23];
    const float* gate1 = (const float*)d_in[24];
    const float* lam1  = (const float*)d_in[25];
    const float* lng1  = (const float*)d_in[26];
    const float* lnb1  = (const float*)d_in[27];
    const float* Wout  = (const float*)d_in[28];
    const float* bout  = (const float*)d_in[29];

    const int N = in_sizes[2] / HD;
    const int E = in_sizes[7] / 2;

    int*   cnt   = (int*)d_ws;
    int*   fillc = cnt + N;
    int*   offs  = fillc + N;
    int*   part  = offs + N;
    int*   tot   = part + 128;
    int2*  srcw  = (int2*)(tot + 4);
    u16*   wlh   = (u16*)(srcw + E);
    u16*   wll   = wlh + 16384;
    u16*   wch   = wll + 16384;
    u16*   wcl   = wch + 16384;
    u16*   woh   = wcl + 16384;
    u16*   wol   = woh + 8192;
    float* bc    = (float*)(wol + 8192);
    float* buf   = bc + 128;             // agg_norm fp32

    hipMemsetAsync(cnt, 0, (size_t)2 * N * sizeof(int), stream);
    hipMemsetAsync(tot, 0, sizeof(int), stream);

    dim3 blk(256);
    const int gE = (E + 255) / 256;
    const int NB = (N + SCAN_E - 1) / SCAN_E;

    k_prep <<<gE + 97, blk, 0, stream>>>(edge2, cnt, E, gE,
                                         Wl1, W01, W11, Wout, bl1, b01, b11,
                                         gate1, wlh, wll, wch, wcl, woh, wol, bc);
    k_scan1<<<NB, blk, 0, stream>>>(cnt, offs, part, tot, N);
    k_fillw<<<gE, blk, 0, stream>>>(edge2, tB, tC, lam1, offs, part, fillc, srcw, E);

    const int gN64 = (N * 64 + 255) / 256;
    k_gather<<<gN64, blk, 0, stream>>>(xB, srcw, offs, part, cnt, buf, N);

    const int GB = (N + 127) / 128;
    k_fused<<<GB, blk, 0, stream>>>(xC, buf, cnt, wlh, wll, wch, wcl, woh, wol,
                                    bc, lng1, lnb1, bout, (float*)d_out, N);
}